// Round 7
// baseline (411.056 us; speedup 1.0000x reference)
//
#include <hip/hip_runtime.h>
#include <cstdint>

// LeNet-5 forward, B=16384. R7: C1 and C3 as implicit-GEMM MFMA
// (mfma_f32_16x16x32_f16, f32 accumulate), 16 samples per block.
// Plan-A memory map (proven <= ws by R6):
//   S2P u32[588][16384] @ 0            (38,535,168)  adjacent col-pairs
//   XP  u32[512][ 8192] @ 38,535,168   (16,777,216)  per-chunk, front only
//   S4H f16[400][16384] @ 38,535,168   (13,107,200)  after front (XP dead)
//   H5P u32[ 60][16384] @ 0            ( 3,932,160)  after c3 (S2P dead)
//   H6P u32[ 42][16384] @ 4,194,304    ( 2,752,512)

typedef unsigned int u32;
typedef _Float16 f16x8 __attribute__((ext_vector_type(8)));
typedef float f32x4 __attribute__((ext_vector_type(4)));

union U32H2 { u32 u; _Float16 h[2]; };
union AB { u32 u[4]; f16x8 v; };

__device__ __forceinline__ float f16lo(u32 v) { U32H2 a; a.u = v; return (float)a.h[0]; }
__device__ __forceinline__ float f16hi(u32 v) { U32H2 a; a.u = v; return (float)a.h[1]; }
__device__ __forceinline__ u32 packh2(float a, float b) {
    U32H2 x; x.h[0] = (_Float16)a; x.h[1] = (_Float16)b; return x.u;
}

// A*tanh(S*v), S=2/3: tanh(y) = 1 - 2/(exp(2y)+1), 2y = (4/3)v
__device__ __forceinline__ float tact(float v) {
    float e = __expf(1.3333333333f * v);
    return 1.7159f * (1.0f - 2.0f * __builtin_amdgcn_rcpf(e + 1.0f));
}

__device__ const int C3MASKBITS[16] = {0x07,0x0E,0x1C,0x38,0x31,0x23,0x0F,0x1E,
                                       0x3C,0x39,0x33,0x27,0x1B,0x36,0x2D,0x3F};

// ---------------- transpose: x chunk (8192,1024) f32 -> xp u32[512][8192] ---
__global__ __launch_bounds__(256) void k_tr(const float* __restrict__ x,
                                            u32* __restrict__ xp)
{
    __shared__ _Float16 lds[64 * 66];
    const int t = threadIdx.x;
    const int tb = blockIdx.x * 64;
    const int tp = blockIdx.y * 64;
    #pragma unroll
    for (int i = 0; i < 16; ++i) {
        int idx = i * 256 + t;
        int bl = idx >> 6, pl = idx & 63;
        lds[pl * 66 + bl] = (_Float16)x[(size_t)(tb + bl) * 1024 + tp + pl];
    }
    __syncthreads();
    #pragma unroll
    for (int j = 0; j < 8; ++j) {
        int idx = j * 256 + t;
        int pp = idx >> 6, bl = idx & 63;
        U32H2 u;
        u.h[0] = lds[(2 * pp) * 66 + bl];
        u.h[1] = lds[(2 * pp + 1) * 66 + bl];
        xp[(size_t)(blockIdx.y * 32 + pp) * 8192 + tb + bl] = u.u;
    }
}

// ---------------- C1 + S2 via MFMA, 16 samples/block, grid 512 --------------
// Quad (y,qx) = conv row y, cols 4qx..4qx+3 -> one s2 value per oc.
// B = x rows (y..y+7) col-pairs 2qx..2qx+3 (shared by 4 shifted-A variants).
// A_d[m=oc][k=(ky row)*8+kx] = w1[oc][ky][kx-d].
// S2P adjacent pairs: s2p[ch*98 + oy2*7 + c2][Nglob] = (s2[oy2][2c2], s2[oy2][2c2+1]).
__global__ __launch_bounds__(256) void k_c1(
    const u32* __restrict__ xp,
    const float* __restrict__ w1, const float* __restrict__ b1,
    const float* __restrict__ s2w, const float* __restrict__ s2b,
    u32* __restrict__ s2p, int sbase)
{
    __shared__ u32 xt[32 * 16 * 17];         // [row32][n16][pair16 +1 pad]
    const int t = threadIdx.x;
    const int n0 = blockIdx.x * 16;
    const int lane = t & 63;
    const int n = lane & 15;
    const int g = lane >> 4;                 // 0..3
    const int w = t >> 6;                    // wave id

    {   // stage 512 pair-features x 16 samples
        const int fi = t >> 4, nn = t & 15;
        #pragma unroll 4
        for (int i = 0; i < 32; ++i) {
            int f = i * 16 + fi;
            xt[((f >> 4) * 16 + nn) * 17 + (f & 15)] = xp[(size_t)f * 8192 + n0 + nn];
        }
    }
    __syncthreads();

    // A fragments: 4 shift variants x 2 K-chunks
    AB A[4][2];
    #pragma unroll
    for (int d = 0; d < 4; ++d)
        #pragma unroll
        for (int c = 0; c < 2; ++c)
            #pragma unroll
            for (int j = 0; j < 4; ++j) {
                int ky = c * 4 + g;
                float lo = 0.0f, hi = 0.0f;
                if (n < 6 && ky < 5) {
                    int kx0 = 2 * j, kx1 = 2 * j + 1;
                    if (kx0 >= d && kx0 - d < 5) lo = w1[n * 25 + ky * 5 + kx0 - d];
                    if (kx1 >= d && kx1 - d < 5) hi = w1[n * 25 + ky * 5 + kx1 - d];
                }
                A[d][c].u[j] = packh2(lo, hi);
            }

    float b1v[4], swv[4], sbv[4];
    #pragma unroll
    for (int r = 0; r < 4; ++r) {
        int R = g * 4 + r; int Rc = (R < 6) ? R : 0;
        b1v[r] = b1[Rc]; swv[r] = s2w[Rc]; sbv[r] = s2b[Rc];
    }

    for (int oy2 = w; oy2 < 14; oy2 += 4) {
        float pend[4];
        #pragma unroll
        for (int part = 0; part < 2; ++part) {
            const int y = 2 * oy2 + part;
            #pragma unroll
            for (int qx = 0; qx < 7; ++qx) {
                const int r0 = y + g;
                int r1 = y + 4 + g; if (r1 > 31) r1 = 31;   // ky>4 -> A=0
                AB B0, B1;
                #pragma unroll
                for (int j = 0; j < 4; ++j) {
                    B0.u[j] = xt[(r0 * 16 + n) * 17 + 2 * qx + j];
                    B1.u[j] = xt[(r1 * 16 + n) * 17 + 2 * qx + j];
                }
                f32x4 F[4];
                #pragma unroll
                for (int d = 0; d < 4; ++d) {
                    F[d] = (f32x4){0.0f, 0.0f, 0.0f, 0.0f};
                    F[d] = __builtin_amdgcn_mfma_f32_16x16x32_f16(A[d][0].v, B0.v, F[d], 0, 0, 0);
                    F[d] = __builtin_amdgcn_mfma_f32_16x16x32_f16(A[d][1].v, B1.v, F[d], 0, 0, 0);
                }
                const int col = part * 7 + qx;
                #pragma unroll
                for (int r = 0; r < 4; ++r) {
                    float m4 = 0.25f * (tact(F[0][r] + b1v[r]) + tact(F[1][r] + b1v[r]) +
                                        tact(F[2][r] + b1v[r]) + tact(F[3][r] + b1v[r]));
                    float sv = tact(swv[r] * m4 + sbv[r]);
                    if (col & 1) {
                        int R = g * 4 + r;
                        if (R < 6)
                            s2p[(size_t)(R * 98 + oy2 * 7 + (col >> 1)) * 16384 + sbase + n0 + n]
                                = packh2(pend[r], sv);
                    } else {
                        pend[r] = sv;
                    }
                }
            }
        }
    }
}

// ---------------- C3 + S4 via MFMA, 16 samples/block, grid 1024 -------------
// A[m=oc][K=256]: K-row r = ic*5+ky (30 used of 32), kx padded 5->8.
// B from LDS tile [ic][row14][n16][pair9] (pairs 7,8 zero pad).
__global__ __launch_bounds__(256) void k_c3(
    const u32* __restrict__ s2p,
    const float* __restrict__ w3, const float* __restrict__ b3,
    const float* __restrict__ s4w, const float* __restrict__ s4b,
    _Float16* __restrict__ s4h)
{
    __shared__ u32 sm[6 * 14 * 16 * 9];      // 12096 dwords = 48384 B
    const int t = threadIdx.x;
    const int n0 = blockIdx.x * 16;
    const int lane = t & 63;
    const int n = lane & 15;
    const int g = lane >> 4;
    const int w = t >> 6;

    {   // stage 588 pair-features x 16 samples + zero pads
        const int fi = t >> 4, nn = t & 15;
        #pragma unroll 4
        for (int i = 0; i < 37; ++i) {
            int f = i * 16 + fi;
            if (f < 588) {
                int ic = f / 98, rem = f % 98;
                int row = rem / 7, c2 = rem % 7;
                sm[((ic * 14 + row) * 16 + nn) * 9 + c2] = s2p[(size_t)f * 16384 + n0 + nn];
            }
        }
        for (int i = t; i < 2688; i += 256) {
            int pr = i >> 1;                 // 0..1343 = (ic*14+row)*16+n
            sm[pr * 9 + 7 + (i & 1)] = 0u;
        }
    }
    __syncthreads();

    // A fragments (8 K-chunks), dense-masked weights
    AB A[8];
    #pragma unroll
    for (int c = 0; c < 8; ++c) {
        int r = c * 4 + g;
        bool conn = false;
        int ic = 0, ky = 0;
        if (r < 30) {
            ic = r / 5; ky = r % 5;
            conn = (C3MASKBITS[n] >> ic) & 1;
        }
        #pragma unroll
        for (int j = 0; j < 4; ++j) {
            float lo = 0.0f, hi = 0.0f;
            if (conn) {
                int kx0 = 2 * j, kx1 = 2 * j + 1;
                if (kx0 < 5) lo = w3[(n * 6 + ic) * 25 + ky * 5 + kx0];
                if (kx1 < 5) hi = w3[(n * 6 + ic) * 25 + ky * 5 + kx1];
            }
            A[c].u[j] = packh2(lo, hi);
        }
    }

    int pre[8];
    #pragma unroll
    for (int c = 0; c < 8; ++c) {
        int r = c * 4 + g; if (r > 29) r = 29;       // clamped row (A=0 there)
        int ic = r / 5, ky = r % 5;
        pre[c] = ((ic * 14 + ky) * 16 + n) * 9;
    }

    float b3v[4], s4wv[4], s4bv[4];
    #pragma unroll
    for (int r = 0; r < 4; ++r) {
        int R = g * 4 + r;
        b3v[r] = b3[R]; s4wv[r] = s4w[R]; s4bv[r] = s4b[R];
    }

    const int qs = (w == 0) ? 0 : 1 + w * 6;         // 7,6,6,6 quads per wave
    const int qe = qs + ((w == 0) ? 7 : 6);
    for (int q = qs; q < qe; ++q) {
        float pacc[4] = {0.0f, 0.0f, 0.0f, 0.0f};
        #pragma unroll
        for (int d = 0; d < 4; ++d) {
            const int f = q * 4 + d;
            const int oy = f / 10, ox = f % 10;      // wave-uniform
            f32x4 acc = (f32x4){0.0f, 0.0f, 0.0f, 0.0f};
            const int p0 = ox >> 1;
            if (ox & 1) {
                #pragma unroll
                for (int c = 0; c < 8; ++c) {
                    int ab = pre[c] + oy * 144 + p0;
                    u32 d0 = sm[ab], d1 = sm[ab + 1], d2 = sm[ab + 2],
                        d3 = sm[ab + 3], d4 = sm[ab + 4];
                    AB B;
                    B.u[0] = (d0 >> 16) | (d1 << 16);
                    B.u[1] = (d1 >> 16) | (d2 << 16);
                    B.u[2] = (d2 >> 16) | (d3 << 16);
                    B.u[3] = (d3 >> 16) | (d4 << 16);
                    acc = __builtin_amdgcn_mfma_f32_16x16x32_f16(A[c].v, B.v, acc, 0, 0, 0);
                }
            } else {
                #pragma unroll
                for (int c = 0; c < 8; ++c) {
                    int ab = pre[c] + oy * 144 + p0;
                    AB B;
                    B.u[0] = sm[ab];     B.u[1] = sm[ab + 1];
                    B.u[2] = sm[ab + 2]; B.u[3] = sm[ab + 3];
                    acc = __builtin_amdgcn_mfma_f32_16x16x32_f16(A[c].v, B.v, acc, 0, 0, 0);
                }
            }
            #pragma unroll
            for (int r = 0; r < 4; ++r) pacc[r] += tact(acc[r] + b3v[r]);
        }
        #pragma unroll
        for (int r = 0; r < 4; ++r) {
            int R = g * 4 + r;
            float sv = tact(0.25f * pacc[r] * s4wv[r] + s4bv[r]);
            s4h[(size_t)(R * 25 + q) * 16384 + n0 + n] = (_Float16)sv;
        }
    }
}

// ---------------- C5: 120-ch GEMV over flat 400, grid (64, 12) --------------
__global__ __launch_bounds__(256) void k_c5(
    const _Float16* __restrict__ s4h, const float* __restrict__ w5,
    const float* __restrict__ b5, u32* __restrict__ h5p, int nb)
{
    const int sl = blockIdx.x * 256 + threadIdx.x;
    const int chg = blockIdx.y;
    float acc[10];
    #pragma unroll
    for (int c = 0; c < 10; ++c) acc[c] = b5[chg * 10 + c];
    #pragma unroll 4
    for (int i = 0; i < 400; ++i) {
        const float v = (float)s4h[(size_t)i * nb + sl];
        #pragma unroll
        for (int c = 0; c < 10; ++c)
            acc[c] += v * w5[(size_t)(chg * 10 + c) * 400 + i];
    }
    #pragma unroll
    for (int j = 0; j < 5; ++j)
        h5p[(size_t)(chg * 5 + j) * nb + sl] =
            packh2(tact(acc[2 * j]), tact(acc[2 * j + 1]));
}

// ---------------- F6: 84-out GEMV over 60 h5 pairs, grid (64, 6) ------------
__global__ __launch_bounds__(256) void k_f6(
    const u32* __restrict__ h5p, const float* __restrict__ f6w,
    const float* __restrict__ f6b, u32* __restrict__ h6p, int nb)
{
    const int sl = blockIdx.x * 256 + threadIdx.x;
    const int og = blockIdx.y;
    float hv[120];
    #pragma unroll
    for (int i = 0; i < 60; ++i) {
        const u32 v = h5p[(size_t)i * nb + sl];
        hv[2 * i]     = f16lo(v);
        hv[2 * i + 1] = f16hi(v);
    }
    float acc[14];
    #pragma unroll
    for (int o = 0; o < 14; ++o) acc[o] = f6b[og * 14 + o];
    #pragma unroll 4
    for (int i = 0; i < 120; ++i) {
        #pragma unroll
        for (int o = 0; o < 14; ++o)
            acc[o] += hv[i] * f6w[(size_t)(og * 14 + o) * 120 + i];
    }
    #pragma unroll
    for (int j = 0; j < 7; ++j)
        h6p[(size_t)(og * 7 + j) * nb + sl] =
            packh2(tact(acc[2 * j]), tact(acc[2 * j + 1]));
}

// ---------------- RBF head, grid (64, 5) ------------------------------------
__global__ __launch_bounds__(256) void k_rbf(
    const u32* __restrict__ h6p, const float* __restrict__ rbf,
    float* __restrict__ out, int nb)
{
    const int sl = blockIdx.x * 256 + threadIdx.x;
    const int gy = blockIdx.y;
    float hv[84];
    #pragma unroll
    for (int i = 0; i < 42; ++i) {
        const u32 v = h6p[(size_t)i * nb + sl];
        hv[2 * i]     = f16lo(v);
        hv[2 * i + 1] = f16hi(v);
    }
    #pragma unroll
    for (int a = 0; a < 2; ++a) {
        const int c = 2 * gy + a;
        float acc = 0.0f;
        #pragma unroll 4
        for (int i = 0; i < 84; ++i) {
            float d = hv[i] - rbf[c * 84 + i];
            acc += d * d;
        }
        out[(size_t)sl * 10 + c] = acc;
    }
}

extern "C" void kernel_launch(void* const* d_in, const int* in_sizes, int n_in,
                              void* d_out, int out_size, void* d_ws, size_t ws_size,
                              hipStream_t stream)
{
    const float* x    = (const float*)d_in[0];
    const float* w1   = (const float*)d_in[1];
    const float* b1   = (const float*)d_in[2];
    const float* s2w  = (const float*)d_in[3];
    const float* s2b  = (const float*)d_in[4];
    const float* w3   = (const float*)d_in[5];
    const float* b3   = (const float*)d_in[6];
    const float* s4w  = (const float*)d_in[7];
    const float* s4b  = (const float*)d_in[8];
    const float* w5   = (const float*)d_in[9];
    const float* b5   = (const float*)d_in[10];
    const float* f6w  = (const float*)d_in[11];
    const float* f6b  = (const float*)d_in[12];
    const float* rbfw = (const float*)d_in[13];
    float* out = (float*)d_out;
    char* ws = (char*)d_ws;

    u32*      S2P = (u32*)(ws);
    u32*      XP  = (u32*)(ws + 38535168);
    _Float16* S4H = (_Float16*)(ws + 38535168);
    u32*      H5P = (u32*)(ws);
    u32*      H6P = (u32*)(ws + 4194304);

    for (int c = 0; c < 2; ++c) {
        k_tr<<<dim3(128, 16), 256, 0, stream>>>(x + (size_t)c * 8192 * 1024, XP);
        k_c1<<<512, 256, 0, stream>>>(XP, w1, b1, s2w, s2b, S2P, c * 8192);
    }
    k_c3<<<1024, 256, 0, stream>>>(S2P, w3, b3, s4w, s4b, S4H);
    k_c5<<<dim3(64, 12), 256, 0, stream>>>(S4H, w5, b5, H5P, 16384);
    k_f6<<<dim3(64, 6), 256, 0, stream>>>(H5P, f6w, f6b, H6P, 16384);
    k_rbf<<<dim3(64, 5), 256, 0, stream>>>(H6P, rbfw, out, 16384);
}